// Round 6
// baseline (254.456 us; speedup 1.0000x reference)
//
#include <hip/hip_runtime.h>
#include <hip/hip_bf16.h>

// MHA forward, MI355X gfx950. bf16 MFMA internal compute, fp32 accumulate.
// Shapes: B=2, T=2048, C=1024, H=16, dk=64.

using short8 = __attribute__((ext_vector_type(8))) short;  // 8 bf16 (4 VGPRs)
using f32x4  = __attribute__((ext_vector_type(4))) float;  // 4 fp32 acc
using fp16x2 = __attribute__((ext_vector_type(2))) __fp16; // cvt_pkrtz result
using half4  = __attribute__((ext_vector_type(4))) _Float16;

#define SCALE_LOG2E 0.18033688011112042f   // 0.125 * log2(e), folded into Wq

__device__ __forceinline__ unsigned short f2bf(float f) {
    union { float f; unsigned u; } v; v.f = f;
    unsigned r = v.u + 0x7fffu + ((v.u >> 16) & 1u);   // RNE
    return (unsigned short)(r >> 16);
}

__device__ __forceinline__ _Float16 bf2h(unsigned short b) {
    union { unsigned u; float f; } v; v.u = ((unsigned)b) << 16;
    return (_Float16)v.f;
}

// async global->LDS, 16B per lane (CK-style uintptr cast)
__device__ __forceinline__ void gld16(const unsigned short* gp, unsigned short* lp) {
    __builtin_amdgcn_global_load_lds(
        (const __attribute__((address_space(1))) void*)(gp),
        (__attribute__((address_space(3))) void*)(unsigned int)(unsigned long long)(lp),
        16, 0, 0);
}

// ---------------- prep: fp32 -> bf16 elementwise (x, Wo) ----------------
__global__ void cvt_bf16(const float* __restrict__ in,
                         unsigned short* __restrict__ out, int n4) {
    int i = blockIdx.x * blockDim.x + threadIdx.x;
    if (i >= n4) return;
    float4 v = ((const float4*)in)[i];
    ushort4 o;
    o.x = f2bf(v.x); o.y = f2bf(v.y); o.z = f2bf(v.z); o.w = f2bf(v.w);
    ((ushort4*)out)[i] = o;
}

// ------- prep: Wq/Wk/Wv [16][1024][64] fp32 -> Wt [48][64][1024] bf16 -------
// Wq rows are pre-scaled by 0.125*log2(e) so attn can use exp2 directly.
__global__ void transpose_w(const float* __restrict__ Wq,
                            const float* __restrict__ Wk,
                            const float* __restrict__ Wv,
                            unsigned short* __restrict__ out) {
    __shared__ float tile[64][65];            // +1 pad: no bank conflicts
    int b = blockIdx.x;                        // 0..767
    int cchunk = b & 15;                       // c0 = cchunk*64
    int h = (b >> 4) & 15;
    int s = b >> 8;                            // 0=q 1=k 2=v
    const float* W = (s == 0) ? Wq : ((s == 1) ? Wk : Wv);
    float sc = (s == 0) ? SCALE_LOG2E : 1.0f;
    const float* src = W + (h * 1024 + cchunk * 64) * 64;   // [64 c][64 k]
    int t = threadIdx.x;
    #pragma unroll
    for (int it = 0; it < 4; ++it) {
        int idx = (it * 256 + t) * 4;          // 0..4095 step 4
        int cc = idx >> 6, kk = idx & 63;
        float4 v = *(const float4*)(src + idx);
        tile[cc][kk + 0] = v.x; tile[cc][kk + 1] = v.y;
        tile[cc][kk + 2] = v.z; tile[cc][kk + 3] = v.w;
    }
    __syncthreads();
    unsigned short* dst = out + (size_t)((s * 16 + h) * 64) * 1024 + cchunk * 64;
    #pragma unroll
    for (int it = 0; it < 16; ++it) {
        int idx = it * 256 + t;                // 0..4095
        int kk = idx >> 6, cc = idx & 63;
        dst[kk * 1024 + cc] = f2bf(tile[cc][kk] * sc);
    }
}

// =======================================================================
// m97-style 128x128 LDS-staged GEMM core (BK=32, 4 waves of 64x64 each).
// =======================================================================
#define GEMM_CORE(A_, B_, m0_, n0_)                                          \
    __shared__ unsigned short Als[128 * 32];                                 \
    __shared__ unsigned short Bls[128 * 32];                                 \
    int wave = threadIdx.x >> 6;                                             \
    int lane = threadIdx.x & 63;                                             \
    int col  = lane & 15;                                                    \
    int quad = lane >> 4;                                                    \
    int m_off = (wave & 1) * 64;                                             \
    int n_off = (wave >> 1) * 64;                                            \
    int ldr = lane >> 2;                                                     \
    int ldc = (lane & 3) * 8;                                                \
    f32x4 acc[4][4] = {};                                                    \
    for (int k0 = 0; k0 < 1024; k0 += 32) {                                  \
        __syncthreads();                                                     \
        _Pragma("unroll")                                                    \
        for (int j = 0; j < 2; ++j) {                                        \
            int row = wave * 32 + j * 16;                                    \
            gld16(A_ + (size_t)(m0_ + row + ldr) * 1024 + k0 + ldc,          \
                  Als + row * 32);                                           \
            gld16(B_ + (size_t)(n0_ + row + ldr) * 1024 + k0 + ldc,          \
                  Bls + row * 32);                                           \
        }                                                                    \
        __syncthreads();                                                     \
        short8 af[4], bf[4];                                                 \
        _Pragma("unroll")                                                    \
        for (int i = 0; i < 4; ++i) {                                        \
            af[i] = *(const short8*)(Als + (m_off + i * 16 + col) * 32 + quad * 8); \
            bf[i] = *(const short8*)(Bls + (n_off + i * 16 + col) * 32 + quad * 8); \
        }                                                                    \
        _Pragma("unroll")                                                    \
        for (int mb = 0; mb < 4; ++mb)                                       \
            _Pragma("unroll")                                                \
            for (int nb = 0; nb < 4; ++nb)                                   \
                acc[mb][nb] = __builtin_amdgcn_mfma_f32_16x16x32_bf16(       \
                    af[mb], bf[nb], acc[mb][nb], 0, 0, 0);                   \
    }

// ---------------- QKV projection GEMM ----------------
__global__ __launch_bounds__(256) void qkv_gemm(
        const unsigned short* __restrict__ xb,
        const unsigned short* __restrict__ Wt,
        unsigned short* __restrict__ qkv) {
    int m0 = blockIdx.x * 128;
    int n0 = blockIdx.y * 128;
    GEMM_CORE(xb, Wt, m0, n0)
    #pragma unroll
    for (int nb = 0; nb < 4; ++nb) {
        int n = n0 + n_off + nb * 16 + col;
        int sh = n >> 6, d = n & 63;           // sh = s*16+h
        int s_ = sh >> 4, h_ = sh & 15;
        #pragma unroll
        for (int mb = 0; mb < 4; ++mb)
            #pragma unroll
            for (int r = 0; r < 4; ++r) {
                int m = m0 + m_off + mb * 16 + quad * 4 + r;  // b*2048+t
                int b_ = m >> 11, t_ = m & 2047;
                qkv[((size_t)((s_ * 2 + b_) * 16 + h_) * 2048 + t_) * 64 + d] =
                    f2bf(acc[mb][nb][r]);
            }
    }
}

// ---------------- output projection GEMM + bias ----------------
__global__ __launch_bounds__(256) void oproj(
        const unsigned short* __restrict__ A,
        const unsigned short* __restrict__ Bw,
        const float* __restrict__ bo,
        float* __restrict__ y) {
    int m0 = blockIdx.x * 128;
    int n0 = blockIdx.y * 128;
    GEMM_CORE(A, Bw, m0, n0)
    #pragma unroll
    for (int nb = 0; nb < 4; ++nb) {
        int n = n0 + n_off + nb * 16 + col;
        float bias = bo[n];
        #pragma unroll
        for (int mb = 0; mb < 4; ++mb)
            #pragma unroll
            for (int r = 0; r < 4; ++r) {
                int m = m0 + m_off + mb * 16 + quad * 4 + r;
                y[(size_t)m * 1024 + n] = acc[mb][nb][r] + bias;
            }
    }
}

// ---- V transpose: [bh][2048][64] bf16 -> [bh][64][2048] f16 ----
__global__ __launch_bounds__(256) void transpose_v(
        const unsigned short* __restrict__ V,
        _Float16* __restrict__ vT) {
    __shared__ unsigned int tile[64][65];
    int bh = blockIdx.y;
    int t0 = blockIdx.x * 64;
    const unsigned short* src = V + ((size_t)bh * 2048 + t0) * 64;
    int i = threadIdx.x;
    #pragma unroll
    for (int p = 0; p < 2; ++p) {
        int idx = p * 256 + i;
        int r = idx >> 3, c = (idx & 7) * 8;
        short8 v = *(const short8*)(src + r * 64 + c);
        #pragma unroll
        for (int j = 0; j < 8; ++j)
            tile[r][c + j] = (unsigned short)v[j];
    }
    __syncthreads();
    _Float16* dst = vT + (size_t)bh * 64 * 2048 + t0;
    int d = i >> 2, ts = (i & 3) * 16;
    half4 o0, o1, o2, o3;
    #pragma unroll
    for (int j = 0; j < 4; ++j) {
        o0[j] = bf2h((unsigned short)tile[ts +      j][d]);
        o1[j] = bf2h((unsigned short)tile[ts +  4 + j][d]);
        o2[j] = bf2h((unsigned short)tile[ts +  8 + j][d]);
        o3[j] = bf2h((unsigned short)tile[ts + 12 + j][d]);
    }
    *(half4*)(dst + (size_t)d * 2048 + ts)      = o0;
    *(half4*)(dst + (size_t)d * 2048 + ts + 4)  = o1;
    *(half4*)(dst + (size_t)d * 2048 + ts + 8)  = o2;
    *(half4*)(dst + (size_t)d * 2048 + ts + 12) = o3;
}

// ---------------- causal flash attention, KV-split-2, S^T trick ----------------
// qkv [3][32bh][2048][64] bf16 (Q prescaled, K), vt16 [32bh][64][2048] f16
// -> aout [2][2048][1024] bf16.
// Computes S^T = K·Q^T via mfma(kf,qf): C-layout [kv=quad*4+r][q=col] is
// exactly the A-frag layout of mfma_f32_16x16x16f16 -> PV needs NO LDS.
__global__ __launch_bounds__(256, 4) void attn(
        const unsigned short* __restrict__ qkv,
        const _Float16* __restrict__ vt16,
        unsigned short* __restrict__ aout) {
    __shared__ float O_comb[2][64][33];            // 16896 B (stride 33)
    __shared__ float L_comb[2][2][2][16];          //  1024 B [sl][parity][qb][q]
    int wave = threadIdx.x >> 6;
    int lane = threadIdx.x & 63;
    int col  = lane & 15;
    int quad = lane >> 4;
    int sl     = wave >> 1;                    // strip within block (0,1)
    int parity = wave & 1;                     // KV-block parity
    int bh   = blockIdx.x & 31;
    int pairidx = 31 - (blockIdx.x >> 5);      // reversed: longest strips first
    int strip = pairidx * 2 + sl;              // 0..63
    int q0 = strip * 32;
    const unsigned short* q  = qkv + (size_t)bh * 2048 * 64;
    const unsigned short* k  = qkv + (size_t)(32 + bh) * 2048 * 64;
    const _Float16* vt = vt16 + (size_t)bh * 64 * 2048;

    short8 qf[2][2];
    #pragma unroll
    for (int qb = 0; qb < 2; ++qb)
        #pragma unroll
        for (int h = 0; h < 2; ++h)
            qf[qb][h] = *(const short8*)(q + (size_t)(q0 + qb * 16 + col) * 64 + h * 32 + quad * 8);

    f32x4 o[2][4] = {};
    float l[2] = {0.f, 0.f};

    int n_iter = (q0 + 95) >> 6;               // ceil((q0+32)/64)
    for (int it = parity; it < n_iter; it += 2) {
        int kv0 = it * 64;
        bool diag = (kv0 + 63 > q0);
        #pragma unroll
        for (int kvb = 0; kvb < 4; ++kvb) {
            int kvbase = kv0 + kvb * 16;
            // S^T block: [kv 16][q 16] per qb, via swapped-operand MFMA
            short8 kf0 = *(const short8*)(k + (size_t)(kvbase + col) * 64 + quad * 8);
            short8 kf1 = *(const short8*)(k + (size_t)(kvbase + col) * 64 + 32 + quad * 8);
            f32x4 st[2] = {};
            #pragma unroll
            for (int qb = 0; qb < 2; ++qb) {
                st[qb] = __builtin_amdgcn_mfma_f32_16x16x32_bf16(kf0, qf[qb][0], st[qb], 0, 0, 0);
                st[qb] = __builtin_amdgcn_mfma_f32_16x16x32_bf16(kf1, qf[qb][1], st[qb], 0, 0, 0);
            }
            // V B-frags (f16) for this 16-kv block
            half4 vf[4];
            #pragma unroll
            for (int nb = 0; nb < 4; ++nb)
                vf[nb] = *(const half4*)(vt + (size_t)(nb * 16 + col) * 2048 + kvbase + quad * 4);
            #pragma unroll
            for (int qb = 0; qb < 2; ++qb) {
                float p0 = __builtin_amdgcn_exp2f(st[qb][0]);
                float p1 = __builtin_amdgcn_exp2f(st[qb][1]);
                float p2 = __builtin_amdgcn_exp2f(st[qb][2]);
                float p3 = __builtin_amdgcn_exp2f(st[qb][3]);
                if (diag) {                       // wave-uniform branch
                    int qg  = q0 + qb * 16 + col;
                    int kvg = kvbase + quad * 4;
                    p0 = (kvg + 0 > qg) ? 0.f : p0;
                    p1 = (kvg + 1 > qg) ? 0.f : p1;
                    p2 = (kvg + 2 > qg) ? 0.f : p2;
                    p3 = (kvg + 3 > qg) ? 0.f : p3;
                }
                l[qb] += (p0 + p1) + (p2 + p3);
                union { fp16x2 h2[2]; half4 h4; } cvt;
                cvt.h2[0] = __builtin_amdgcn_cvt_pkrtz(p0, p1);
                cvt.h2[1] = __builtin_amdgcn_cvt_pkrtz(p2, p3);
                half4 pf = cvt.h4;
                #pragma unroll
                for (int nb = 0; nb < 4; ++nb)
                    o[qb][nb] = __builtin_amdgcn_mfma_f32_16x16x16f16(pf, vf[nb], o[qb][nb], 0, 0, 0);
            }
        }
    }
    // reduce l across quads (partials live per q=col in 4 quad groups)
    #pragma unroll
    for (int qb = 0; qb < 2; ++qb) {
        float lr = l[qb];
        lr += __shfl_xor(lr, 16);
        lr += __shfl_xor(lr, 32);
        l[qb] = lr;
    }
    if (quad == 0) {
        L_comb[sl][parity][0][col] = l[0];
        L_comb[sl][parity][1][col] = l[1];
    }
    if (parity == 1) {
        #pragma unroll
        for (int qb = 0; qb < 2; ++qb)
            #pragma unroll
            for (int nb = 0; nb < 4; ++nb)
                #pragma unroll
                for (int r = 0; r < 4; ++r)
                    O_comb[sl][lane][qb * 16 + nb * 4 + r] = o[qb][nb][r];
    }
    __syncthreads();
    if (parity == 0) {
        int b_ = bh >> 4, h_ = bh & 15;
        #pragma unroll
        for (int qb = 0; qb < 2; ++qb)
            #pragma unroll
            for (int r = 0; r < 4; ++r) {
                int qi = quad * 4 + r;
                float inv_l = 1.0f / (L_comb[sl][0][qb][qi] + L_comb[sl][1][qb][qi]);
                int t_ = q0 + qb * 16 + qi;
                #pragma unroll
                for (int nb = 0; nb < 4; ++nb) {
                    float ov = o[qb][nb][r] + O_comb[sl][lane][qb * 16 + nb * 4 + r];
                    aout[(size_t)(b_ * 2048 + t_) * 1024 + h_ * 64 + nb * 16 + col] =
                        f2bf(ov * inv_l);
                }
            }
    }
}

extern "C" void kernel_launch(void* const* d_in, const int* in_sizes, int n_in,
                              void* d_out, int out_size, void* d_ws, size_t ws_size,
                              hipStream_t stream) {
    const float* x  = (const float*)d_in[0];
    const float* Wq = (const float*)d_in[1];
    const float* Wk = (const float*)d_in[2];
    const float* Wv = (const float*)d_in[3];
    const float* Wo = (const float*)d_in[4];
    const float* bo = (const float*)d_in[5];
    float* y = (float*)d_out;

    unsigned short* xb   = (unsigned short*)d_ws;     // 4096*1024
    unsigned short* Wt   = xb   + 4194304;            // 3072*1024
    unsigned short* Wob  = Wt   + 3145728;            // 1024*1024
    unsigned short* qkvb = Wob  + 1048576;            // 3*32*2048*64
    unsigned short* vTb  = qkvb + 12582912;           // 32*64*2048 (f16)
    unsigned short* aout = vTb  + 4194304;            // 4096*1024

    cvt_bf16<<<4096, 256, 0, stream>>>(x,  xb,  1048576);
    cvt_bf16<<<1024, 256, 0, stream>>>(Wo, Wob, 262144);
    transpose_w<<<768, 256, 0, stream>>>(Wq, Wk, Wv, Wt);
    qkv_gemm<<<dim3(32, 24), 256, 0, stream>>>(xb, Wt, qkvb);
    transpose_v<<<dim3(32, 32), 256, 0, stream>>>(qkvb + (size_t)64 * 2048 * 64,
                                                  (_Float16*)vTb);
    attn<<<1024, 256, 0, stream>>>(qkvb, (const _Float16*)vTb, aout);
    oproj<<<dim3(32, 8), 256, 0, stream>>>(aout, Wob, bo, y);
}

// Round 7
// 191.465 us; speedup vs baseline: 1.3290x; 1.3290x over previous
//
#include <hip/hip_runtime.h>
#include <hip/hip_bf16.h>

// MHA forward, MI355X gfx950. bf16 MFMA internal compute, fp32 accumulate.
// Shapes: B=2, T=2048, C=1024, H=16, dk=64.

using short8 = __attribute__((ext_vector_type(8))) short;  // 8 bf16 (4 VGPRs)
using f32x4  = __attribute__((ext_vector_type(4))) float;  // 4 fp32 acc
using fp16x2 = __attribute__((ext_vector_type(2))) __fp16; // cvt_pkrtz result
using half4  = __attribute__((ext_vector_type(4))) _Float16;
using half8  = __attribute__((ext_vector_type(8))) _Float16;

#define SCALE_LOG2E 0.18033688011112042f   // 0.125 * log2(e), folded into Wq

__device__ __forceinline__ unsigned short f2bf(float f) {
    union { float f; unsigned u; } v; v.f = f;
    unsigned r = v.u + 0x7fffu + ((v.u >> 16) & 1u);   // RNE
    return (unsigned short)(r >> 16);
}

// async global->LDS, 16B per lane (CK-style uintptr cast)
__device__ __forceinline__ void gld16(const unsigned short* gp, unsigned short* lp) {
    __builtin_amdgcn_global_load_lds(
        (const __attribute__((address_space(1))) void*)(gp),
        (__attribute__((address_space(3))) void*)(unsigned int)(unsigned long long)(lp),
        16, 0, 0);
}

// ---------------- prep: fp32 -> bf16 elementwise (x, Wo) ----------------
__global__ void cvt_bf16(const float* __restrict__ in,
                         unsigned short* __restrict__ out, int n4) {
    int i = blockIdx.x * blockDim.x + threadIdx.x;
    if (i >= n4) return;
    float4 v = ((const float4*)in)[i];
    ushort4 o;
    o.x = f2bf(v.x); o.y = f2bf(v.y); o.z = f2bf(v.z); o.w = f2bf(v.w);
    ((ushort4*)out)[i] = o;
}

// ------- prep: Wq/Wk/Wv [16][1024][64] fp32 -> Wt [48][64][1024] bf16 -------
// Wq rows are pre-scaled by 0.125*log2(e) so attn can use exp2 directly.
__global__ void transpose_w(const float* __restrict__ Wq,
                            const float* __restrict__ Wk,
                            const float* __restrict__ Wv,
                            unsigned short* __restrict__ out) {
    __shared__ float tile[64][65];            // +1 pad: no bank conflicts
    int b = blockIdx.x;                        // 0..767
    int cchunk = b & 15;                       // c0 = cchunk*64
    int h = (b >> 4) & 15;
    int s = b >> 8;                            // 0=q 1=k 2=v
    const float* W = (s == 0) ? Wq : ((s == 1) ? Wk : Wv);
    float sc = (s == 0) ? SCALE_LOG2E : 1.0f;
    const float* src = W + (h * 1024 + cchunk * 64) * 64;   // [64 c][64 k]
    int t = threadIdx.x;
    #pragma unroll
    for (int it = 0; it < 4; ++it) {
        int idx = (it * 256 + t) * 4;          // 0..4095 step 4
        int cc = idx >> 6, kk = idx & 63;
        float4 v = *(const float4*)(src + idx);
        tile[cc][kk + 0] = v.x; tile[cc][kk + 1] = v.y;
        tile[cc][kk + 2] = v.z; tile[cc][kk + 3] = v.w;
    }
    __syncthreads();
    unsigned short* dst = out + (size_t)((s * 16 + h) * 64) * 1024 + cchunk * 64;
    #pragma unroll
    for (int it = 0; it < 16; ++it) {
        int idx = it * 256 + t;                // 0..4095
        int kk = idx >> 6, cc = idx & 63;
        dst[kk * 1024 + cc] = f2bf(tile[cc][kk] * sc);
    }
}

// =======================================================================
// m97-style 128x128 LDS-staged GEMM core (BK=32, 4 waves of 64x64 each).
// =======================================================================
#define GEMM_CORE(A_, B_, m0_, n0_)                                          \
    __shared__ unsigned short Als[128 * 32];                                 \
    __shared__ unsigned short Bls[128 * 32];                                 \
    int wave = threadIdx.x >> 6;                                             \
    int lane = threadIdx.x & 63;                                             \
    int col  = lane & 15;                                                    \
    int quad = lane >> 4;                                                    \
    int m_off = (wave & 1) * 64;                                             \
    int n_off = (wave >> 1) * 64;                                            \
    int ldr = lane >> 2;                                                     \
    int ldc = (lane & 3) * 8;                                                \
    f32x4 acc[4][4] = {};                                                    \
    for (int k0 = 0; k0 < 1024; k0 += 32) {                                  \
        __syncthreads();                                                     \
        _Pragma("unroll")                                                    \
        for (int j = 0; j < 2; ++j) {                                        \
            int row = wave * 32 + j * 16;                                    \
            gld16(A_ + (size_t)(m0_ + row + ldr) * 1024 + k0 + ldc,          \
                  Als + row * 32);                                           \
            gld16(B_ + (size_t)(n0_ + row + ldr) * 1024 + k0 + ldc,          \
                  Bls + row * 32);                                           \
        }                                                                    \
        __syncthreads();                                                     \
        short8 af[4], bf[4];                                                 \
        _Pragma("unroll")                                                    \
        for (int i = 0; i < 4; ++i) {                                        \
            af[i] = *(const short8*)(Als + (m_off + i * 16 + col) * 32 + quad * 8); \
            bf[i] = *(const short8*)(Bls + (n_off + i * 16 + col) * 32 + quad * 8); \
        }                                                                    \
        _Pragma("unroll")                                                    \
        for (int mb = 0; mb < 4; ++mb)                                       \
            _Pragma("unroll")                                                \
            for (int nb = 0; nb < 4; ++nb)                                   \
                acc[mb][nb] = __builtin_amdgcn_mfma_f32_16x16x32_bf16(       \
                    af[mb], bf[nb], acc[mb][nb], 0, 0, 0);                   \
    }

// ---------------- QKV projection GEMM ----------------
// Writes Q in [bh][t][64] bf16; K in fragment layout
// kfrag[bh][kv16][h][lane][8] bf16; V in vfrag[bh][kv32][nb][lane][8] f16.
// Fragment layouts are exactly what attn's MFMA operands need -> attn loads
// are lane-contiguous (no gathers). Branch on blockIdx.y>>3 is block-uniform.
__global__ __launch_bounds__(256) void qkv_gemm(
        const unsigned short* __restrict__ xb,
        const unsigned short* __restrict__ Wt,
        unsigned short* __restrict__ qB,
        unsigned short* __restrict__ kfrag,
        _Float16* __restrict__ vfrag) {
    int m0 = blockIdx.x * 128;
    int n0 = blockIdx.y * 128;
    GEMM_CORE(xb, Wt, m0, n0)
    int sel = blockIdx.y >> 3;                 // 0=Q 1=K 2=V
    #pragma unroll
    for (int nb = 0; nb < 4; ++nb) {
        int n = n0 + n_off + nb * 16 + col;
        int d10 = n & 1023;                    // index within Q/K/V slab
        int h_ = d10 >> 6, d = d10 & 63;
        if (sel == 0) {
            #pragma unroll
            for (int mb = 0; mb < 4; ++mb)
                #pragma unroll
                for (int r = 0; r < 4; ++r) {
                    int m = m0 + m_off + mb * 16 + quad * 4 + r;
                    int b_ = m >> 11, t_ = m & 2047;
                    qB[((size_t)(b_ * 16 + h_) * 2048 + t_) * 64 + d] =
                        f2bf(acc[mb][nb][r]);
                }
        } else if (sel == 1) {
            int hK = d >> 5, quadk = (d >> 3) & 3, j = d & 7;
            #pragma unroll
            for (int mb = 0; mb < 4; ++mb)
                #pragma unroll
                for (int r = 0; r < 4; ++r) {
                    int m = m0 + m_off + mb * 16 + quad * 4 + r;
                    int b_ = m >> 11, t_ = m & 2047;
                    int bh = b_ * 16 + h_;
                    kfrag[((((size_t)bh * 128 + (t_ >> 4)) * 2 + hK) * 64 +
                           quadk * 16 + (t_ & 15)) * 8 + j] = f2bf(acc[mb][nb][r]);
                }
        } else {
            int nbv = d >> 4, colv = d & 15;
            #pragma unroll
            for (int mb = 0; mb < 4; ++mb)
                #pragma unroll
                for (int r = 0; r < 4; ++r) {
                    int m = m0 + m_off + mb * 16 + quad * 4 + r;
                    int b_ = m >> 11, t_ = m & 2047;
                    int bh = b_ * 16 + h_;
                    vfrag[((((size_t)bh * 64 + (t_ >> 5)) * 4 + nbv) * 64 +
                           ((t_ >> 2) & 3) * 16 + colv) * 8 +
                          ((t_ >> 4) & 1) * 4 + (t_ & 3)] = (_Float16)acc[mb][nb][r];
                }
        }
    }
}

// ---------------- output projection GEMM + bias ----------------
__global__ __launch_bounds__(256) void oproj(
        const unsigned short* __restrict__ A,
        const unsigned short* __restrict__ Bw,
        const float* __restrict__ bo,
        float* __restrict__ y) {
    int m0 = blockIdx.x * 128;
    int n0 = blockIdx.y * 128;
    GEMM_CORE(A, Bw, m0, n0)
    #pragma unroll
    for (int nb = 0; nb < 4; ++nb) {
        int n = n0 + n_off + nb * 16 + col;
        float bias = bo[n];
        #pragma unroll
        for (int mb = 0; mb < 4; ++mb)
            #pragma unroll
            for (int r = 0; r < 4; ++r) {
                int m = m0 + m_off + mb * 16 + quad * 4 + r;
                y[(size_t)m * 1024 + n] = acc[mb][nb][r] + bias;
            }
    }
}

// ---------------- causal flash attention, KV-split-2, S^T trick ----------------
// qB [32bh][2048][64] bf16 (Q prescaled), kfrag/vfrag pre-fragmented.
// Computes S^T = K·Q^T via mfma(kf,qf): C-layout [kv=quad*4+r][q=col] is
// exactly the A-frag layout of mfma_f32_16x16x16f16 -> PV needs NO LDS.
// All in-loop loads are lane-contiguous 16B (coalesced, 8 cache lines/instr).
__global__ __launch_bounds__(256, 4) void attn(
        const unsigned short* __restrict__ qB,
        const unsigned short* __restrict__ kfrag,
        const _Float16* __restrict__ vfrag,
        unsigned short* __restrict__ aout) {
    __shared__ float O_comb[2][64][33];            // 16896 B (stride 33)
    __shared__ float L_comb[2][2][2][16];          //  1024 B [sl][parity][qb][q]
    int wave = threadIdx.x >> 6;
    int lane = threadIdx.x & 63;
    int col  = lane & 15;
    int quad = lane >> 4;
    int sl     = wave >> 1;                    // strip within block (0,1)
    int parity = wave & 1;                     // KV-block parity
    int bh   = blockIdx.x & 31;
    int pairidx = 31 - (blockIdx.x >> 5);      // reversed: longest strips first
    int strip = pairidx * 2 + sl;              // 0..63
    int q0 = strip * 32;
    const unsigned short* q = qB + (size_t)bh * 2048 * 64;
    const unsigned short* kf_base = kfrag + (size_t)bh * 128 * 2 * 512;
    const _Float16*       vf_base = vfrag + (size_t)bh * 64 * 4 * 512;

    short8 qf[2][2];
    #pragma unroll
    for (int qb = 0; qb < 2; ++qb)
        #pragma unroll
        for (int h = 0; h < 2; ++h)
            qf[qb][h] = *(const short8*)(q + (size_t)(q0 + qb * 16 + col) * 64 + h * 32 + quad * 8);

    f32x4 o[2][4] = {};
    float l[2] = {0.f, 0.f};

    int n_iter = (q0 + 95) >> 6;               // ceil((q0+32)/64)
    for (int it = parity; it < n_iter; it += 2) {
        int kv0 = it * 64;
        bool diag = (kv0 + 63 > q0);
        #pragma unroll
        for (int kv32 = 0; kv32 < 2; ++kv32) {
            // V fragments for this 32-kv half: one 16B load per nb
            half8 vv[4];
            #pragma unroll
            for (int nb = 0; nb < 4; ++nb)
                vv[nb] = *(const half8*)(vf_base +
                    (((size_t)((kv0 >> 5) + kv32) * 4 + nb) * 64 + lane) * 8);
            #pragma unroll
            for (int par = 0; par < 2; ++par) {
                int kvb = kv32 * 2 + par;
                int kvbase = kv0 + kvb * 16;
                int K16 = (kv0 >> 4) + kvb;
                // K A-frags: lane-contiguous 16B loads
                short8 kf0 = *(const short8*)(kf_base + (((size_t)K16 * 2 + 0) * 64 + lane) * 8);
                short8 kf1 = *(const short8*)(kf_base + (((size_t)K16 * 2 + 1) * 64 + lane) * 8);
                f32x4 st[2] = {};
                #pragma unroll
                for (int qb = 0; qb < 2; ++qb) {
                    st[qb] = __builtin_amdgcn_mfma_f32_16x16x32_bf16(kf0, qf[qb][0], st[qb], 0, 0, 0);
                    st[qb] = __builtin_amdgcn_mfma_f32_16x16x32_bf16(kf1, qf[qb][1], st[qb], 0, 0, 0);
                }
                #pragma unroll
                for (int qb = 0; qb < 2; ++qb) {
                    float p0 = __builtin_amdgcn_exp2f(st[qb][0]);
                    float p1 = __builtin_amdgcn_exp2f(st[qb][1]);
                    float p2 = __builtin_amdgcn_exp2f(st[qb][2]);
                    float p3 = __builtin_amdgcn_exp2f(st[qb][3]);
                    if (diag) {                       // wave-uniform branch
                        int qg  = q0 + qb * 16 + col;
                        int kvg = kvbase + quad * 4;
                        p0 = (kvg + 0 > qg) ? 0.f : p0;
                        p1 = (kvg + 1 > qg) ? 0.f : p1;
                        p2 = (kvg + 2 > qg) ? 0.f : p2;
                        p3 = (kvg + 3 > qg) ? 0.f : p3;
                    }
                    l[qb] += (p0 + p1) + (p2 + p3);
                    union { fp16x2 h2[2]; half4 h4; } cvt;
                    cvt.h2[0] = __builtin_amdgcn_cvt_pkrtz(p0, p1);
                    cvt.h2[1] = __builtin_amdgcn_cvt_pkrtz(p2, p3);
                    half4 pf = cvt.h4;
                    #pragma unroll
                    for (int nb = 0; nb < 4; ++nb) {
                        half4 vf = (par == 0)
                            ? __builtin_shufflevector(vv[nb], vv[nb], 0, 1, 2, 3)
                            : __builtin_shufflevector(vv[nb], vv[nb], 4, 5, 6, 7);
                        o[qb][nb] = __builtin_amdgcn_mfma_f32_16x16x16f16(pf, vf, o[qb][nb], 0, 0, 0);
                    }
                }
            }
        }
    }
    // reduce l across quads (partials live per q=col in 4 quad groups)
    #pragma unroll
    for (int qb = 0; qb < 2; ++qb) {
        float lr = l[qb];
        lr += __shfl_xor(lr, 16);
        lr += __shfl_xor(lr, 32);
        l[qb] = lr;
    }
    if (quad == 0) {
        L_comb[sl][parity][0][col] = l[0];
        L_comb[sl][parity][1][col] = l[1];
    }
    if (parity == 1) {
        #pragma unroll
        for (int qb = 0; qb < 2; ++qb)
            #pragma unroll
            for (int nb = 0; nb < 4; ++nb)
                #pragma unroll
                for (int r = 0; r < 4; ++r)
                    O_comb[sl][lane][qb * 16 + nb * 4 + r] = o[qb][nb][r];
    }
    __syncthreads();
    if (parity == 0) {
        int b_ = bh >> 4, h_ = bh & 15;
        #pragma unroll
        for (int qb = 0; qb < 2; ++qb)
            #pragma unroll
            for (int r = 0; r < 4; ++r) {
                int qi = quad * 4 + r;
                float inv_l = 1.0f / (L_comb[sl][0][qb][qi] + L_comb[sl][1][qb][qi]);
                int t_ = q0 + qb * 16 + qi;
                #pragma unroll
                for (int nb = 0; nb < 4; ++nb) {
                    float ov = o[qb][nb][r] + O_comb[sl][lane][qb * 16 + nb * 4 + r];
                    aout[(size_t)(b_ * 2048 + t_) * 1024 + h_ * 64 + nb * 16 + col] =
                        f2bf(ov * inv_l);
                }
            }
    }
}

extern "C" void kernel_launch(void* const* d_in, const int* in_sizes, int n_in,
                              void* d_out, int out_size, void* d_ws, size_t ws_size,
                              hipStream_t stream) {
    const float* x  = (const float*)d_in[0];
    const float* Wq = (const float*)d_in[1];
    const float* Wk = (const float*)d_in[2];
    const float* Wv = (const float*)d_in[3];
    const float* Wo = (const float*)d_in[4];
    const float* bo = (const float*)d_in[5];
    float* y = (float*)d_out;

    unsigned short* xb    = (unsigned short*)d_ws;    // 4096*1024
    unsigned short* Wt    = xb    + 4194304;          // 3072*1024
    unsigned short* Wob   = Wt    + 3145728;          // 1024*1024
    unsigned short* qBb   = Wob   + 1048576;          // 32*2048*64
    unsigned short* kfr   = qBb   + 4194304;          // 32*128*2*512
    unsigned short* vfr   = kfr   + 4194304;          // 32*64*4*512 (f16)
    unsigned short* aout  = vfr   + 4194304;          // 4096*1024

    cvt_bf16<<<4096, 256, 0, stream>>>(x,  xb,  1048576);
    cvt_bf16<<<1024, 256, 0, stream>>>(Wo, Wob, 262144);
    transpose_w<<<768, 256, 0, stream>>>(Wq, Wk, Wv, Wt);
    qkv_gemm<<<dim3(32, 24), 256, 0, stream>>>(xb, Wt, qBb, kfr, (_Float16*)vfr);
    attn<<<1024, 256, 0, stream>>>(qBb, kfr, (const _Float16*)vfr, aout);
    oproj<<<dim3(32, 8), 256, 0, stream>>>(aout, Wob, bo, y);
}

// Round 8
// 181.984 us; speedup vs baseline: 1.3982x; 1.0521x over previous
//
#include <hip/hip_runtime.h>
#include <hip/hip_bf16.h>

// MHA forward, MI355X gfx950. bf16 MFMA internal compute, fp32 accumulate.
// Shapes: B=2, T=2048, C=1024, H=16, dk=64.

using short8 = __attribute__((ext_vector_type(8))) short;  // 8 bf16 (4 VGPRs)
using f32x4  = __attribute__((ext_vector_type(4))) float;  // 4 fp32 acc
using fp16x2 = __attribute__((ext_vector_type(2))) __fp16; // cvt_pkrtz result
using half4  = __attribute__((ext_vector_type(4))) _Float16;
using half8  = __attribute__((ext_vector_type(8))) _Float16;

#define SCALE_LOG2E 0.18033688011112042f   // 0.125 * log2(e), folded into Wq

__device__ __forceinline__ unsigned short f2bf(float f) {
    union { float f; unsigned u; } v; v.f = f;
    unsigned r = v.u + 0x7fffu + ((v.u >> 16) & 1u);   // RNE
    return (unsigned short)(r >> 16);
}

// async global->LDS, 16B per lane (CK-style uintptr cast)
__device__ __forceinline__ void gld16(const unsigned short* gp, unsigned short* lp) {
    __builtin_amdgcn_global_load_lds(
        (const __attribute__((address_space(1))) void*)(gp),
        (__attribute__((address_space(3))) void*)(unsigned int)(unsigned long long)(lp),
        16, 0, 0);
}

// ---------------- prep: fp32 -> bf16 elementwise (x, Wo) ----------------
__global__ void cvt_bf16(const float* __restrict__ in,
                         unsigned short* __restrict__ out, int n4) {
    int i = blockIdx.x * blockDim.x + threadIdx.x;
    if (i >= n4) return;
    float4 v = ((const float4*)in)[i];
    ushort4 o;
    o.x = f2bf(v.x); o.y = f2bf(v.y); o.z = f2bf(v.z); o.w = f2bf(v.w);
    ((ushort4*)out)[i] = o;
}

// ------- prep: Wq/Wk/Wv [16][1024][64] fp32 -> Wt [48][64][1024] bf16 -------
// Wq rows are pre-scaled by 0.125*log2(e) so attn can use exp2 directly.
__global__ void transpose_w(const float* __restrict__ Wq,
                            const float* __restrict__ Wk,
                            const float* __restrict__ Wv,
                            unsigned short* __restrict__ out) {
    __shared__ float tile[64][65];            // +1 pad: no bank conflicts
    int b = blockIdx.x;                        // 0..767
    int cchunk = b & 15;                       // c0 = cchunk*64
    int h = (b >> 4) & 15;
    int s = b >> 8;                            // 0=q 1=k 2=v
    const float* W = (s == 0) ? Wq : ((s == 1) ? Wk : Wv);
    float sc = (s == 0) ? SCALE_LOG2E : 1.0f;
    const float* src = W + (h * 1024 + cchunk * 64) * 64;   // [64 c][64 k]
    int t = threadIdx.x;
    #pragma unroll
    for (int it = 0; it < 4; ++it) {
        int idx = (it * 256 + t) * 4;          // 0..4095 step 4
        int cc = idx >> 6, kk = idx & 63;
        float4 v = *(const float4*)(src + idx);
        tile[cc][kk + 0] = v.x; tile[cc][kk + 1] = v.y;
        tile[cc][kk + 2] = v.z; tile[cc][kk + 3] = v.w;
    }
    __syncthreads();
    unsigned short* dst = out + (size_t)((s * 16 + h) * 64) * 1024 + cchunk * 64;
    #pragma unroll
    for (int it = 0; it < 16; ++it) {
        int idx = it * 256 + t;                // 0..4095
        int kk = idx >> 6, cc = idx & 63;
        dst[kk * 1024 + cc] = f2bf(tile[cc][kk] * sc);
    }
}

// =======================================================================
// 128x128 LDS-staged GEMM core, BK=64 (16 iters, half the barriers of BK=32).
// Staging via global_load_lds 16B/lane; k-chunk XOR-swizzled by row&7 on the
// global-source side (LDS dest of global_load_lds is fixed lane*16), reader
// un-swizzles with lc ^ (col&7) -> 2-way bank aliasing max (free).
// =======================================================================
#define GEMM_CORE(A_, B_, m0_, n0_)                                          \
    __shared__ unsigned short Als[128 * 64];                                 \
    __shared__ unsigned short Bls[128 * 64];                                 \
    int wave = threadIdx.x >> 6;                                             \
    int lane = threadIdx.x & 63;                                             \
    int col  = lane & 15;                                                    \
    int quad = lane >> 4;                                                    \
    int m_off = (wave & 1) * 64;                                             \
    int n_off = (wave >> 1) * 64;                                            \
    int ldr = lane >> 3;                                                     \
    int ldc = ((lane & 7) ^ ldr) * 8;                                        \
    f32x4 acc[4][4] = {};                                                    \
    for (int k0 = 0; k0 < 1024; k0 += 64) {                                  \
        __syncthreads();                                                     \
        _Pragma("unroll")                                                    \
        for (int j = 0; j < 4; ++j) {                                        \
            int row = wave * 32 + j * 8;                                     \
            gld16(A_ + (size_t)(m0_ + row + ldr) * 1024 + k0 + ldc,          \
                  Als + row * 64);                                           \
            gld16(B_ + (size_t)(n0_ + row + ldr) * 1024 + k0 + ldc,          \
                  Bls + row * 64);                                           \
        }                                                                    \
        __syncthreads();                                                     \
        _Pragma("unroll")                                                    \
        for (int kh = 0; kh < 2; ++kh) {                                     \
            short8 af[4], bf[4];                                             \
            _Pragma("unroll")                                                \
            for (int i = 0; i < 4; ++i) {                                    \
                int lc = kh * 4 + quad;                                      \
                int sw = (lc ^ (col & 7)) * 8;                               \
                af[i] = *(const short8*)(Als + (m_off + i * 16 + col) * 64 + sw); \
                bf[i] = *(const short8*)(Bls + (n_off + i * 16 + col) * 64 + sw); \
            }                                                                \
            _Pragma("unroll")                                                \
            for (int mb = 0; mb < 4; ++mb)                                   \
                _Pragma("unroll")                                            \
                for (int nb = 0; nb < 4; ++nb)                               \
                    acc[mb][nb] = __builtin_amdgcn_mfma_f32_16x16x32_bf16(   \
                        af[mb], bf[nb], acc[mb][nb], 0, 0, 0);               \
        }                                                                    \
    }

// ---------------- QKV projection GEMM ----------------
// Writes Q in [bh][t][64] bf16; K in fragment layout
// kfrag[bh][kv16][h][lane][8] bf16; V in vfrag[bh][kv32][nb][lane][8] f16.
__global__ __launch_bounds__(256) void qkv_gemm(
        const unsigned short* __restrict__ xb,
        const unsigned short* __restrict__ Wt,
        unsigned short* __restrict__ qB,
        unsigned short* __restrict__ kfrag,
        _Float16* __restrict__ vfrag) {
    int m0 = blockIdx.x * 128;
    int n0 = blockIdx.y * 128;
    GEMM_CORE(xb, Wt, m0, n0)
    int sel = blockIdx.y >> 3;                 // 0=Q 1=K 2=V
    #pragma unroll
    for (int nb = 0; nb < 4; ++nb) {
        int n = n0 + n_off + nb * 16 + col;
        int d10 = n & 1023;                    // index within Q/K/V slab
        int h_ = d10 >> 6, d = d10 & 63;
        if (sel == 0) {
            #pragma unroll
            for (int mb = 0; mb < 4; ++mb)
                #pragma unroll
                for (int r = 0; r < 4; ++r) {
                    int m = m0 + m_off + mb * 16 + quad * 4 + r;
                    int b_ = m >> 11, t_ = m & 2047;
                    qB[((size_t)(b_ * 16 + h_) * 2048 + t_) * 64 + d] =
                        f2bf(acc[mb][nb][r]);
                }
        } else if (sel == 1) {
            int hK = d >> 5, quadk = (d >> 3) & 3, j = d & 7;
            #pragma unroll
            for (int mb = 0; mb < 4; ++mb)
                #pragma unroll
                for (int r = 0; r < 4; ++r) {
                    int m = m0 + m_off + mb * 16 + quad * 4 + r;
                    int b_ = m >> 11, t_ = m & 2047;
                    int bh = b_ * 16 + h_;
                    kfrag[((((size_t)bh * 128 + (t_ >> 4)) * 2 + hK) * 64 +
                           quadk * 16 + (t_ & 15)) * 8 + j] = f2bf(acc[mb][nb][r]);
                }
        } else {
            int nbv = d >> 4, colv = d & 15;
            #pragma unroll
            for (int mb = 0; mb < 4; ++mb) {
                int m = m0 + m_off + mb * 16 + quad * 4;   // r=0 base, t&3=0
                int b_ = m >> 11, t_ = m & 2047;
                int bh = b_ * 16 + h_;
                half4 hv;
                hv[0] = (_Float16)acc[mb][nb][0]; hv[1] = (_Float16)acc[mb][nb][1];
                hv[2] = (_Float16)acc[mb][nb][2]; hv[3] = (_Float16)acc[mb][nb][3];
                *(half4*)(vfrag + ((((size_t)bh * 64 + (t_ >> 5)) * 4 + nbv) * 64 +
                          ((t_ >> 2) & 3) * 16 + colv) * 8 + ((t_ >> 4) & 1) * 4) = hv;
            }
        }
    }
}

// ---------------- output projection GEMM + bias ----------------
__global__ __launch_bounds__(256) void oproj(
        const unsigned short* __restrict__ A,
        const unsigned short* __restrict__ Bw,
        const float* __restrict__ bo,
        float* __restrict__ y) {
    int m0 = blockIdx.x * 128;
    int n0 = blockIdx.y * 128;
    GEMM_CORE(A, Bw, m0, n0)
    #pragma unroll
    for (int nb = 0; nb < 4; ++nb) {
        int n = n0 + n_off + nb * 16 + col;
        float bias = bo[n];
        #pragma unroll
        for (int mb = 0; mb < 4; ++mb)
            #pragma unroll
            for (int r = 0; r < 4; ++r) {
                int m = m0 + m_off + mb * 16 + quad * 4 + r;
                y[(size_t)m * 1024 + n] = acc[mb][nb][r] + bias;
            }
    }
}

// ---------------- causal flash attention, KV-split-2, S^T trick ----------------
// qB [32bh][2048][64] bf16 (Q prescaled), kfrag/vfrag pre-fragmented.
// S^T = K·Q^T via mfma(kf,qf); PV via f16 16x16x16 with in-register P.
// Software pipeline: next 32-kv half's K/V fragments prefetched during the
// current half's exp+PV work (register double-buffer).
__global__ __launch_bounds__(256, 3) void attn(
        const unsigned short* __restrict__ qB,
        const unsigned short* __restrict__ kfrag,
        const _Float16* __restrict__ vfrag,
        unsigned short* __restrict__ aout) {
    __shared__ float O_comb[2][64][33];            // 16896 B (stride 33)
    __shared__ float L_comb[2][2][2][16];          //  1024 B [sl][parity][qb][q]
    int wave = threadIdx.x >> 6;
    int lane = threadIdx.x & 63;
    int col  = lane & 15;
    int quad = lane >> 4;
    int sl     = wave >> 1;                    // strip within block (0,1)
    int parity = wave & 1;                     // KV-block parity
    int bh   = blockIdx.x & 31;
    int pairidx = 31 - (blockIdx.x >> 5);      // reversed: longest strips first
    int strip = pairidx * 2 + sl;              // 0..63
    int q0 = strip * 32;
    const unsigned short* q = qB + (size_t)bh * 2048 * 64;
    const unsigned short* kf_base = kfrag + (size_t)bh * 128 * 2 * 512;
    const _Float16*       vf_base = vfrag + (size_t)bh * 64 * 4 * 512;

    short8 qf[2][2];
    #pragma unroll
    for (int qb = 0; qb < 2; ++qb)
        #pragma unroll
        for (int h = 0; h < 2; ++h)
            qf[qb][h] = *(const short8*)(q + (size_t)(q0 + qb * 16 + col) * 64 + h * 32 + quad * 8);

    f32x4 o[2][4] = {};
    float l[2] = {0.f, 0.f};

    struct KV { short8 kf[2][2]; half8 vv[4]; };
    KV bufA, bufB;

    auto load_half = [&](int it, int kv32, KV& b) {
        int K16 = it * 4 + kv32 * 2;
        #pragma unroll
        for (int p = 0; p < 2; ++p)
            #pragma unroll
            for (int h = 0; h < 2; ++h)
                b.kf[p][h] = *(const short8*)(kf_base +
                    (((size_t)(K16 + p) * 2 + h) * 64 + lane) * 8);
        #pragma unroll
        for (int nb = 0; nb < 4; ++nb)
            b.vv[nb] = *(const half8*)(vf_base +
                (((size_t)(it * 2 + kv32) * 4 + nb) * 64 + lane) * 8);
    };

    auto compute_half = [&](int it, int kv32, KV& b) {
        int kv0 = it * 64;
        bool diag = (kv0 + 63 > q0);
        #pragma unroll
        for (int par = 0; par < 2; ++par) {
            int kvbase = kv0 + kv32 * 32 + par * 16;
            f32x4 st[2] = {};
            #pragma unroll
            for (int qb = 0; qb < 2; ++qb) {
                st[qb] = __builtin_amdgcn_mfma_f32_16x16x32_bf16(b.kf[par][0], qf[qb][0], st[qb], 0, 0, 0);
                st[qb] = __builtin_amdgcn_mfma_f32_16x16x32_bf16(b.kf[par][1], qf[qb][1], st[qb], 0, 0, 0);
            }
            #pragma unroll
            for (int qb = 0; qb < 2; ++qb) {
                float p0 = __builtin_amdgcn_exp2f(st[qb][0]);
                float p1 = __builtin_amdgcn_exp2f(st[qb][1]);
                float p2 = __builtin_amdgcn_exp2f(st[qb][2]);
                float p3 = __builtin_amdgcn_exp2f(st[qb][3]);
                if (diag) {                       // wave-uniform branch
                    int qg  = q0 + qb * 16 + col;
                    int kvg = kvbase + quad * 4;
                    p0 = (kvg + 0 > qg) ? 0.f : p0;
                    p1 = (kvg + 1 > qg) ? 0.f : p1;
                    p2 = (kvg + 2 > qg) ? 0.f : p2;
                    p3 = (kvg + 3 > qg) ? 0.f : p3;
                }
                l[qb] += (p0 + p1) + (p2 + p3);
                union { fp16x2 h2[2]; half4 h4; } cvt;
                cvt.h2[0] = __builtin_amdgcn_cvt_pkrtz(p0, p1);
                cvt.h2[1] = __builtin_amdgcn_cvt_pkrtz(p2, p3);
                half4 pf = cvt.h4;
                #pragma unroll
                for (int nb = 0; nb < 4; ++nb) {
                    half4 vf = (par == 0)
                        ? __builtin_shufflevector(b.vv[nb], b.vv[nb], 0, 1, 2, 3)
                        : __builtin_shufflevector(b.vv[nb], b.vv[nb], 4, 5, 6, 7);
                    o[qb][nb] = __builtin_amdgcn_mfma_f32_16x16x16f16(pf, vf, o[qb][nb], 0, 0, 0);
                }
            }
        }
    };

    int n_iter = (q0 + 95) >> 6;               // ceil((q0+32)/64)
    if (parity < n_iter) load_half(parity, 0, bufA);
    for (int it = parity; it < n_iter; it += 2) {
        load_half(it, 1, bufB);                // prefetch 2nd half of this iter
        compute_half(it, 0, bufA);
        if (it + 2 < n_iter) load_half(it + 2, 0, bufA);   // prefetch next iter
        compute_half(it, 1, bufB);
    }

    // reduce l across quads (partials live per q=col in 4 quad groups)
    #pragma unroll
    for (int qb = 0; qb < 2; ++qb) {
        float lr = l[qb];
        lr += __shfl_xor(lr, 16);
        lr += __shfl_xor(lr, 32);
        l[qb] = lr;
    }
    if (quad == 0) {
        L_comb[sl][parity][0][col] = l[0];
        L_comb[sl][parity][1][col] = l[1];
    }
    if (parity == 1) {
        #pragma unroll
        for (int qb = 0; qb < 2; ++qb)
            #pragma unroll
            for (int nb = 0; nb < 4; ++nb)
                #pragma unroll
                for (int r = 0; r < 4; ++r)
                    O_comb[sl][lane][qb * 16 + nb * 4 + r] = o[qb][nb][r];
    }
    __syncthreads();
    if (parity == 0) {
        int b_ = bh >> 4, h_ = bh & 15;
        #pragma unroll
        for (int qb = 0; qb < 2; ++qb)
            #pragma unroll
            for (int r = 0; r < 4; ++r) {
                int qi = quad * 4 + r;
                float inv_l = 1.0f / (L_comb[sl][0][qb][qi] + L_comb[sl][1][qb][qi]);
                int t_ = q0 + qb * 16 + qi;
                #pragma unroll
                for (int nb = 0; nb < 4; ++nb) {
                    float ov = o[qb][nb][r] + O_comb[sl][lane][qb * 16 + nb * 4 + r];
                    aout[(size_t)(b_ * 2048 + t_) * 1024 + h_ * 64 + nb * 16 + col] =
                        f2bf(ov * inv_l);
                }
            }
    }
}

extern "C" void kernel_launch(void* const* d_in, const int* in_sizes, int n_in,
                              void* d_out, int out_size, void* d_ws, size_t ws_size,
                              hipStream_t stream) {
    const float* x  = (const float*)d_in[0];
    const float* Wq = (const float*)d_in[1];
    const float* Wk = (const float*)d_in[2];
    const float* Wv = (const float*)d_in[3];
    const float* Wo = (const float*)d_in[4];
    const float* bo = (const float*)d_in[5];
    float* y = (float*)d_out;

    unsigned short* xb    = (unsigned short*)d_ws;    // 4096*1024
    unsigned short* Wt    = xb    + 4194304;          // 3072*1024
    unsigned short* Wob   = Wt    + 3145728;          // 1024*1024
    unsigned short* qBb   = Wob   + 1048576;          // 32*2048*64
    unsigned short* kfr   = qBb   + 4194304;          // 32*128*2*512
    unsigned short* vfr   = kfr   + 4194304;          // 32*64*4*512 (f16)
    unsigned short* aout  = vfr   + 4194304;          // 4096*1024

    cvt_bf16<<<4096, 256, 0, stream>>>(x,  xb,  1048576);
    cvt_bf16<<<1024, 256, 0, stream>>>(Wo, Wob, 262144);
    transpose_w<<<768, 256, 0, stream>>>(Wq, Wk, Wv, Wt);
    qkv_gemm<<<dim3(32, 24), 256, 0, stream>>>(xb, Wt, qBb, kfr, (_Float16*)vfr);
    attn<<<1024, 256, 0, stream>>>(qBb, kfr, (const _Float16*)vfr, aout);
    oproj<<<dim3(32, 8), 256, 0, stream>>>(aout, Wob, bo, y);
}